// Round 1
// baseline (923.844 us; speedup 1.0000x reference)
//
#include <hip/hip_runtime.h>

#define NN 100000
#define EE 640000

typedef float f32x4 __attribute__((ext_vector_type(4)));
typedef __bf16 bf16x8 __attribute__((ext_vector_type(8)));
typedef unsigned short u16x4 __attribute__((ext_vector_type(4)));
typedef unsigned short u16x8 __attribute__((ext_vector_type(8)));

__device__ __forceinline__ unsigned short f2b(float f) {
  unsigned u = __float_as_uint(f);
  u += 0x7fffu + ((u >> 16) & 1u);   // RNE; inputs are finite
  return (unsigned short)(u >> 16);
}
__device__ __forceinline__ float b2f(unsigned short h) {
  return __uint_as_float(((unsigned)h) << 16);
}

// ---------- transpose + XOR-swizzle + bf16-convert weights (7 chunks of 128x128) ----------
__global__ void prep_wt(const float* __restrict__ w0, const float* __restrict__ w1,
                        const float* __restrict__ w2, const float* __restrict__ w3,
                        const float* __restrict__ w4, const float* __restrict__ w5,
                        unsigned short* __restrict__ wt) {
  int chunk = blockIdx.x;
  const float* W;
  int kc = 0;
  switch (chunk) {
    case 0: W = w0; break;
    case 1: W = w1; break;
    case 2: W = w2; break;
    case 3: W = w3; break;
    case 4: W = w4; break;
    case 5: W = w4; kc = 128; break;
    default: W = w5; break;
  }
  unsigned short* out = wt + chunk * 16384;
  for (int idx = threadIdx.x; idx < 16384; idx += 256) {
    int k = idx >> 7, c = idx & 127;                   // coalesced read of W[k][c]
    float v = W[(kc + k) * 128 + c];
    out[c * 128 + (((k >> 3) ^ (c & 7)) << 3) + (k & 7)] = f2b(v);
  }
}

// ---------- fused GEMM (+BN-stat accumulation) ----------
// MODE 0: A = raw fp32 (feat)
// MODE 1: A = bf16 h, transform relu(h*sc+sh)
// MODE 2: K=256 concat: chunk0 = MODE1 on Aptr, chunk1 = A2[row]*1/max(cnt,1)
template <int NCHK, int MODE>
__global__ __launch_bounds__(256, 2) void gemm_bn(
    const void* __restrict__ Aptr, const float* __restrict__ A2,
    const float* __restrict__ cnt, const float* __restrict__ sc,
    const float* __restrict__ sh, const unsigned short* __restrict__ Wt,
    unsigned short* __restrict__ Hout, float* __restrict__ colsum,
    float* __restrict__ colsumsq) {
  __shared__ unsigned short Alds[16384];
  __shared__ unsigned short Wlds[16384];
  const int tid = threadIdx.x;
  const int row0 = blockIdx.x * 128;
  const int lane = tid & 63;
  const int wid = tid >> 6;
  const int wm = (wid >> 1) * 64, wn = (wid & 1) * 64;

  f32x4 acc[4][4] = {};

#pragma unroll
  for (int ch = 0; ch < NCHK; ++ch) {
    if (ch) __syncthreads();
    // ---- stage A (transform -> bf16 -> swizzled LDS) ----
    {
      const int r8 = tid >> 5;
      const int kq = (tid & 31) * 4;
      f32x4 scv = {}, shv = {};
      if (MODE != 0) {
        scv = *(const f32x4*)(sc + kq);
        shv = *(const f32x4*)(sh + kq);
      }
#pragma unroll
      for (int it = 0; it < 16; ++it) {
        int r = it * 8 + r8;
        int grow = row0 + r;
        float v0 = 0.f, v1 = 0.f, v2 = 0.f, v3 = 0.f;
        if (grow < NN) {
          if (MODE == 0) {
            f32x4 t = *(const f32x4*)((const float*)Aptr + grow * 128 + kq);
            v0 = t.x; v1 = t.y; v2 = t.z; v3 = t.w;
          } else if (MODE == 1 || ch == 0) {
            const unsigned short* Ah = (const unsigned short*)Aptr;
            u16x4 t = *(const u16x4*)(Ah + grow * 128 + kq);
            v0 = fmaxf(b2f(t.x) * scv.x + shv.x, 0.f);
            v1 = fmaxf(b2f(t.y) * scv.y + shv.y, 0.f);
            v2 = fmaxf(b2f(t.z) * scv.z + shv.z, 0.f);
            v3 = fmaxf(b2f(t.w) * scv.w + shv.w, 0.f);
          } else {
            f32x4 t = *(const f32x4*)(A2 + grow * 128 + kq);
            float rc = 1.f / fmaxf(cnt[grow], 1.f);
            v0 = t.x * rc; v1 = t.y * rc; v2 = t.z * rc; v3 = t.w * rc;
          }
        }
        int off = r * 128 + (((kq >> 3) ^ (r & 7)) << 3) + (kq & 7);
        u16x4 p;
        p.x = f2b(v0); p.y = f2b(v1); p.z = f2b(v2); p.w = f2b(v3);
        *(u16x4*)&Alds[off] = p;
      }
    }
    // ---- stage Wt (pre-swizzled in global, linear copy) ----
    {
      const unsigned short* wsrc = Wt + ch * 16384;
#pragma unroll
      for (int it = 0; it < 8; ++it) {
        int idx = tid + it * 256;
        *(u16x8*)&Wlds[idx * 8] = *(const u16x8*)(wsrc + idx * 8);
      }
    }
    __syncthreads();
    // ---- MFMA main loop ----
#pragma unroll
    for (int ks = 0; ks < 4; ++ks) {
      const int kk = ks * 32 + (lane >> 4) * 8;
      const int kg = kk >> 3;
      bf16x8 af[4], bfr[4];
#pragma unroll
      for (int m = 0; m < 4; ++m) {
        int rr = wm + m * 16 + (lane & 15);
        af[m] = *(const bf16x8*)&Alds[rr * 128 + ((kg ^ (rr & 7)) << 3)];
      }
#pragma unroll
      for (int n = 0; n < 4; ++n) {
        int cc = wn + n * 16 + (lane & 15);
        bfr[n] = *(const bf16x8*)&Wlds[cc * 128 + ((kg ^ (cc & 7)) << 3)];
      }
#pragma unroll
      for (int m = 0; m < 4; ++m)
#pragma unroll
        for (int n = 0; n < 4; ++n)
          acc[m][n] = __builtin_amdgcn_mfma_f32_16x16x32_bf16(af[m], bfr[n], acc[m][n], 0, 0, 0);
    }
  }

  // ---- stats (zero-padded rows contribute 0) ----
  float s[4] = {0.f, 0.f, 0.f, 0.f}, q[4] = {0.f, 0.f, 0.f, 0.f};
#pragma unroll
  for (int n = 0; n < 4; ++n)
#pragma unroll
    for (int m = 0; m < 4; ++m)
#pragma unroll
      for (int i = 0; i < 4; ++i) {
        float v = acc[m][n][i];
        s[n] += v;
        q[n] += v * v;
      }
#pragma unroll
  for (int n = 0; n < 4; ++n) {
    s[n] += __shfl_xor(s[n], 16);
    s[n] += __shfl_xor(s[n], 32);
    q[n] += __shfl_xor(q[n], 16);
    q[n] += __shfl_xor(q[n], 32);
  }
  if ((lane >> 4) == 0) {
#pragma unroll
    for (int n = 0; n < 4; ++n) {
      unsafeAtomicAdd(&colsum[wn + n * 16 + lane], s[n]);
      unsafeAtomicAdd(&colsumsq[wn + n * 16 + lane], q[n]);
    }
  }
  // ---- store raw h as bf16 ----
  const int rg = lane >> 4, c = lane & 15;
#pragma unroll
  for (int m = 0; m < 4; ++m)
#pragma unroll
    for (int i = 0; i < 4; ++i) {
      int row = row0 + wm + m * 16 + rg * 4 + i;
      if (row < NN) {
#pragma unroll
        for (int n = 0; n < 4; ++n)
          Hout[row * 128 + wn + n * 16 + c] = f2b(acc[m][n][i]);
      }
    }
}

// ---------- finalize BN stats -> per-column scale/shift ----------
__global__ void fin_stats(const float* __restrict__ colsum, const float* __restrict__ colsumsq,
                          const float* __restrict__ g, const float* __restrict__ beta,
                          float* __restrict__ sc, float* __restrict__ sh) {
  int c = threadIdx.x;
  float mu = colsum[c] * (1.f / NN);
  float var = colsumsq[c] * (1.f / NN) - mu * mu;
  float inv = rsqrtf(fmaxf(var, 0.f) + 1e-5f);
  float s = g[c] * inv;
  sc[c] = s;
  sh[c] = beta[c] - mu * s;
}

// ---------- edge gather + normalize + atomic scatter-add ----------
__global__ __launch_bounds__(256) void edge_scatter(
    const unsigned short* __restrict__ h2, const float* __restrict__ sc,
    const float* __restrict__ sh, const int* __restrict__ src,
    const int* __restrict__ dst, float* __restrict__ sums, float* __restrict__ cnt) {
  const int lane = threadIdx.x & 63;
  const int wv = (blockIdx.x << 2) + (threadIdx.x >> 6);
  const int c0 = lane * 2;
  const float s0 = sc[c0], s1 = sc[c0 + 1], t0 = sh[c0], t1 = sh[c0 + 1];
#pragma unroll
  for (int j = 0; j < 4; ++j) {
    int e = (wv << 2) + j;
    if (e >= EE) return;
    int sn = src[e], dn = dst[e];
    unsigned u = *(const unsigned*)(h2 + sn * 128 + c0);
    float x0 = fmaxf(b2f((unsigned short)u) * s0 + t0, 0.f);
    float x1 = fmaxf(b2f((unsigned short)(u >> 16)) * s1 + t1, 0.f);
    unsafeAtomicAdd(&sums[dn * 128 + c0], x0);
    unsafeAtomicAdd(&sums[dn * 128 + c0 + 1], x1);
    if (lane == 0) unsafeAtomicAdd(&cnt[dn], 1.f);
  }
}

// ---------- final normalize to fp32 output ----------
__global__ __launch_bounds__(256) void norm_out(
    const unsigned short* __restrict__ h, const float* __restrict__ sc,
    const float* __restrict__ sh, float* __restrict__ out) {
  int idx = blockIdx.x * 256 + threadIdx.x;
  int e = idx * 8;
  u16x8 v = *(const u16x8*)(h + e);
  int cb = e & 127;
  f32x4 sA = *(const f32x4*)(sc + cb), sB = *(const f32x4*)(sc + cb + 4);
  f32x4 tA = *(const f32x4*)(sh + cb), tB = *(const f32x4*)(sh + cb + 4);
  f32x4 o0, o1;
  o0.x = fmaxf(b2f(v[0]) * sA.x + tA.x, 0.f);
  o0.y = fmaxf(b2f(v[1]) * sA.y + tA.y, 0.f);
  o0.z = fmaxf(b2f(v[2]) * sA.z + tA.z, 0.f);
  o0.w = fmaxf(b2f(v[3]) * sA.w + tA.w, 0.f);
  o1.x = fmaxf(b2f(v[4]) * sB.x + tB.x, 0.f);
  o1.y = fmaxf(b2f(v[5]) * sB.y + tB.y, 0.f);
  o1.z = fmaxf(b2f(v[6]) * sB.z + tB.z, 0.f);
  o1.w = fmaxf(b2f(v[7]) * sB.w + tB.w, 0.f);
  *(f32x4*)(out + e) = o0;
  *(f32x4*)(out + e + 4) = o1;
}

extern "C" void kernel_launch(void* const* d_in, const int* in_sizes, int n_in,
                              void* d_out, int out_size, void* d_ws, size_t ws_size,
                              hipStream_t stream) {
  (void)in_sizes; (void)n_in; (void)out_size; (void)ws_size;
  const float* feat = (const float*)d_in[0];
  const int* src = (const int*)d_in[1];
  const int* dst = (const int*)d_in[2];
  const float* aW1 = (const float*)d_in[3];
  const float* aW2 = (const float*)d_in[4];
  const float* sW1 = (const float*)d_in[5];
  const float* sW2 = (const float*)d_in[6];
  const float* cW1 = (const float*)d_in[7];
  const float* cW2 = (const float*)d_in[8];
  // layer order: 0=aggr1 1=aggr2 2=self1 3=self2 4=comb1 5=comb2
  const float* g[6] = {(const float*)d_in[10], (const float*)d_in[13],
                       (const float*)d_in[16], (const float*)d_in[19],
                       (const float*)d_in[22], (const float*)d_in[25]};
  const float* be[6] = {(const float*)d_in[11], (const float*)d_in[14],
                        (const float*)d_in[17], (const float*)d_in[20],
                        (const float*)d_in[23], (const float*)d_in[26]};

  char* ws = (char*)d_ws;
  unsigned short* WA = (unsigned short*)ws;                    // bf16 h buffer A (also fp32 sums)
  unsigned short* WB = (unsigned short*)(ws + 51200000);       // bf16 h buffer B
  float* sums = (float*)ws;
  float* cnt = (float*)(ws + 102400000);
  float* stats = (float*)(ws + 102800000);                     // 6 x [sum|sumsq|scale|shift] x128
  unsigned short* wt = (unsigned short*)(ws + 103041664 - 229376);
  float* outF = (float*)d_out;
  unsigned short* h4 = (unsigned short*)d_out;                 // park h4 (bf16) in d_out bytes

  float* CS[6]; float* CQ[6]; float* SC[6]; float* SH[6];
  for (int L = 0; L < 6; ++L) {
    CS[L] = stats + L * 512;
    CQ[L] = stats + L * 512 + 128;
    SC[L] = stats + L * 512 + 256;
    SH[L] = stats + L * 512 + 384;
  }

  hipMemsetAsync(ws + 102400000, 0, 412288, stream);           // cnt + stats accumulators
  prep_wt<<<7, 256, 0, stream>>>(aW1, aW2, sW1, sW2, cW1, cW2, wt);

  dim3 gg(782);
  // L1: feat -> h1 (WA)
  gemm_bn<1, 0><<<gg, 256, 0, stream>>>(feat, nullptr, nullptr, nullptr, nullptr,
                                        wt + 0 * 16384, WA, CS[0], CQ[0]);
  fin_stats<<<1, 128, 0, stream>>>(CS[0], CQ[0], g[0], be[0], SC[0], SH[0]);
  // L2: n(h1) -> h2 (WB)
  gemm_bn<1, 1><<<gg, 256, 0, stream>>>(WA, nullptr, nullptr, SC[0], SH[0],
                                        wt + 1 * 16384, WB, CS[1], CQ[1]);
  fin_stats<<<1, 128, 0, stream>>>(CS[1], CQ[1], g[1], be[1], SC[1], SH[1]);
  // L3: feat -> h3 (WA)
  gemm_bn<1, 0><<<gg, 256, 0, stream>>>(feat, nullptr, nullptr, nullptr, nullptr,
                                        wt + 2 * 16384, WA, CS[2], CQ[2]);
  fin_stats<<<1, 128, 0, stream>>>(CS[2], CQ[2], g[2], be[2], SC[2], SH[2]);
  // L4: n(h3) -> h4 (d_out bytes)
  gemm_bn<1, 1><<<gg, 256, 0, stream>>>(WA, nullptr, nullptr, SC[2], SH[2],
                                        wt + 3 * 16384, h4, CS[3], CQ[3]);
  fin_stats<<<1, 128, 0, stream>>>(CS[3], CQ[3], g[3], be[3], SC[3], SH[3]);
  // segment mean: zero sums (WA reused), scatter n(h2)
  hipMemsetAsync(ws, 0, 51200000, stream);
  edge_scatter<<<40000, 256, 0, stream>>>(WB, SC[1], SH[1], src, dst, sums, cnt);
  // L5: [n(h4) | sums/cnt] -> h5 (WB)
  gemm_bn<2, 2><<<gg, 256, 0, stream>>>(h4, sums, cnt, SC[3], SH[3],
                                        wt + 4 * 16384, WB, CS[4], CQ[4]);
  fin_stats<<<1, 128, 0, stream>>>(CS[4], CQ[4], g[4], be[4], SC[4], SH[4]);
  // L6: n(h5) -> h6 (WA)
  gemm_bn<1, 1><<<gg, 256, 0, stream>>>(WB, nullptr, nullptr, SC[4], SH[4],
                                        wt + 6 * 16384, WA, CS[5], CQ[5]);
  fin_stats<<<1, 128, 0, stream>>>(CS[5], CQ[5], g[5], be[5], SC[5], SH[5]);
  // final normalize -> fp32 out
  norm_out<<<6250, 256, 0, stream>>>(WA, SC[5], SH[5], outF);
}

// Round 2
// 499.140 us; speedup vs baseline: 1.8509x; 1.8509x over previous
//
#include <hip/hip_runtime.h>

#define NN 100000
#define EE 640000

typedef float f32x4 __attribute__((ext_vector_type(4)));
typedef __bf16 bf16x8 __attribute__((ext_vector_type(8)));
typedef unsigned short u16x4 __attribute__((ext_vector_type(4)));
typedef unsigned short u16x8 __attribute__((ext_vector_type(8)));

__device__ __forceinline__ unsigned short f2b(float f) {
  unsigned u = __float_as_uint(f);
  u += 0x7fffu + ((u >> 16) & 1u);   // RNE; inputs are finite
  return (unsigned short)(u >> 16);
}
__device__ __forceinline__ float b2f(unsigned short h) {
  return __uint_as_float(((unsigned)h) << 16);
}

// ---------- transpose + XOR-swizzle + bf16-convert weights (7 chunks of 128x128) ----------
__global__ void prep_wt(const float* __restrict__ w0, const float* __restrict__ w1,
                        const float* __restrict__ w2, const float* __restrict__ w3,
                        const float* __restrict__ w4, const float* __restrict__ w5,
                        unsigned short* __restrict__ wt) {
  int chunk = blockIdx.x;
  const float* W;
  int kc = 0;
  switch (chunk) {
    case 0: W = w0; break;
    case 1: W = w1; break;
    case 2: W = w2; break;
    case 3: W = w3; break;
    case 4: W = w4; break;
    case 5: W = w4; kc = 128; break;
    default: W = w5; break;
  }
  unsigned short* out = wt + chunk * 16384;
  for (int idx = threadIdx.x; idx < 16384; idx += 256) {
    int k = idx >> 7, c = idx & 127;                   // coalesced read of W[k][c]
    float v = W[(kc + k) * 128 + c];
    out[c * 128 + (((k >> 3) ^ (c & 7)) << 3) + (k & 7)] = f2b(v);
  }
}

// ---------- fused GEMM (+BN-stat accumulation) ----------
// MODE 0: A = raw fp32 (feat)
// MODE 1: A = bf16 h, transform relu(h*sc+sh)
// MODE 2: K=256 concat: chunk0 = MODE1 on Aptr, chunk1 = raw bf16 from A2 (mean)
template <int NCHK, int MODE>
__global__ __launch_bounds__(256, 2) void gemm_bn(
    const void* __restrict__ Aptr, const unsigned short* __restrict__ A2,
    const float* __restrict__ sc, const float* __restrict__ sh,
    const unsigned short* __restrict__ Wt,
    unsigned short* __restrict__ Hout, float* __restrict__ colsum,
    float* __restrict__ colsumsq) {
  __shared__ unsigned short Alds[16384];
  __shared__ unsigned short Wlds[16384];
  const int tid = threadIdx.x;
  const int row0 = blockIdx.x * 128;
  const int lane = tid & 63;
  const int wid = tid >> 6;
  const int wm = (wid >> 1) * 64, wn = (wid & 1) * 64;

  f32x4 acc[4][4] = {};

#pragma unroll
  for (int ch = 0; ch < NCHK; ++ch) {
    if (ch) __syncthreads();
    // ---- stage A (transform -> bf16 -> swizzled LDS) ----
    {
      const int r8 = tid >> 5;
      const int kq = (tid & 31) * 4;
      f32x4 scv = {}, shv = {};
      if (MODE != 0) {
        scv = *(const f32x4*)(sc + kq);
        shv = *(const f32x4*)(sh + kq);
      }
#pragma unroll
      for (int it = 0; it < 16; ++it) {
        int r = it * 8 + r8;
        int grow = row0 + r;
        float v0 = 0.f, v1 = 0.f, v2 = 0.f, v3 = 0.f;
        if (grow < NN) {
          if (MODE == 0) {
            f32x4 t = *(const f32x4*)((const float*)Aptr + grow * 128 + kq);
            v0 = t.x; v1 = t.y; v2 = t.z; v3 = t.w;
          } else if (MODE == 1 || ch == 0) {
            const unsigned short* Ah = (const unsigned short*)Aptr;
            u16x4 t = *(const u16x4*)(Ah + grow * 128 + kq);
            v0 = fmaxf(b2f(t.x) * scv.x + shv.x, 0.f);
            v1 = fmaxf(b2f(t.y) * scv.y + shv.y, 0.f);
            v2 = fmaxf(b2f(t.z) * scv.z + shv.z, 0.f);
            v3 = fmaxf(b2f(t.w) * scv.w + shv.w, 0.f);
          } else {
            u16x4 t = *(const u16x4*)(A2 + grow * 128 + kq);
            v0 = b2f(t.x); v1 = b2f(t.y); v2 = b2f(t.z); v3 = b2f(t.w);
          }
        }
        int off = r * 128 + (((kq >> 3) ^ (r & 7)) << 3) + (kq & 7);
        u16x4 p;
        p.x = f2b(v0); p.y = f2b(v1); p.z = f2b(v2); p.w = f2b(v3);
        *(u16x4*)&Alds[off] = p;
      }
    }
    // ---- stage Wt (pre-swizzled in global, linear copy) ----
    {
      const unsigned short* wsrc = Wt + ch * 16384;
#pragma unroll
      for (int it = 0; it < 8; ++it) {
        int idx = tid + it * 256;
        *(u16x8*)&Wlds[idx * 8] = *(const u16x8*)(wsrc + idx * 8);
      }
    }
    __syncthreads();
    // ---- MFMA main loop ----
#pragma unroll
    for (int ks = 0; ks < 4; ++ks) {
      const int kk = ks * 32 + (lane >> 4) * 8;
      const int kg = kk >> 3;
      bf16x8 af[4], bfr[4];
#pragma unroll
      for (int m = 0; m < 4; ++m) {
        int rr = wm + m * 16 + (lane & 15);
        af[m] = *(const bf16x8*)&Alds[rr * 128 + ((kg ^ (rr & 7)) << 3)];
      }
#pragma unroll
      for (int n = 0; n < 4; ++n) {
        int cc = wn + n * 16 + (lane & 15);
        bfr[n] = *(const bf16x8*)&Wlds[cc * 128 + ((kg ^ (cc & 7)) << 3)];
      }
#pragma unroll
      for (int m = 0; m < 4; ++m)
#pragma unroll
        for (int n = 0; n < 4; ++n)
          acc[m][n] = __builtin_amdgcn_mfma_f32_16x16x32_bf16(af[m], bfr[n], acc[m][n], 0, 0, 0);
    }
  }

  // ---- stats (zero-padded rows contribute 0) ----
  float s[4] = {0.f, 0.f, 0.f, 0.f}, q[4] = {0.f, 0.f, 0.f, 0.f};
#pragma unroll
  for (int n = 0; n < 4; ++n)
#pragma unroll
    for (int m = 0; m < 4; ++m)
#pragma unroll
      for (int i = 0; i < 4; ++i) {
        float v = acc[m][n][i];
        s[n] += v;
        q[n] += v * v;
      }
#pragma unroll
  for (int n = 0; n < 4; ++n) {
    s[n] += __shfl_xor(s[n], 16);
    s[n] += __shfl_xor(s[n], 32);
    q[n] += __shfl_xor(q[n], 16);
    q[n] += __shfl_xor(q[n], 32);
  }
  if ((lane >> 4) == 0) {
#pragma unroll
    for (int n = 0; n < 4; ++n) {
      unsafeAtomicAdd(&colsum[wn + n * 16 + lane], s[n]);
      unsafeAtomicAdd(&colsumsq[wn + n * 16 + lane], q[n]);
    }
  }
  // ---- store raw h as bf16 ----
  const int rg = lane >> 4, c = lane & 15;
#pragma unroll
  for (int m = 0; m < 4; ++m)
#pragma unroll
    for (int i = 0; i < 4; ++i) {
      int row = row0 + wm + m * 16 + rg * 4 + i;
      if (row < NN) {
#pragma unroll
        for (int n = 0; n < 4; ++n)
          Hout[row * 128 + wn + n * 16 + c] = f2b(acc[m][n][i]);
      }
    }
}

// ---------- finalize BN stats -> per-column scale/shift ----------
__global__ void fin_stats(const float* __restrict__ colsum, const float* __restrict__ colsumsq,
                          const float* __restrict__ g, const float* __restrict__ beta,
                          float* __restrict__ sc, float* __restrict__ sh) {
  int c = threadIdx.x;
  float mu = colsum[c] * (1.f / NN);
  float var = colsumsq[c] * (1.f / NN) - mu * mu;
  float inv = rsqrtf(fmaxf(var, 0.f) + 1e-5f);
  float s = g[c] * inv;
  sc[c] = s;
  sh[c] = beta[c] - mu * s;
}

// ---------- CSR build: histogram, scan, edge-id scatter ----------
__global__ __launch_bounds__(256) void hist_deg(const int* __restrict__ dst,
                                                int* __restrict__ deg) {
  int e = blockIdx.x * 256 + threadIdx.x;
  if (e < EE) atomicAdd(&deg[dst[e]], 1);
}

__global__ __launch_bounds__(256) void scan_part(const int* __restrict__ deg,
                                                 int* __restrict__ part) {
  __shared__ int tmp[256];
  int i = blockIdx.x * 256 + threadIdx.x;
  int t = threadIdx.x;
  tmp[t] = (i < NN) ? deg[i] : 0;
  __syncthreads();
  for (int s = 128; s > 0; s >>= 1) {
    if (t < s) tmp[t] += tmp[t + s];
    __syncthreads();
  }
  if (t == 0) part[blockIdx.x] = tmp[0];
}

__global__ __launch_bounds__(512) void scan_top(int* __restrict__ part) {
  __shared__ int tmp[512];
  int t = threadIdx.x;
  int v = (t < 391) ? part[t] : 0;
  tmp[t] = v;
  __syncthreads();
  for (int s = 1; s < 512; s <<= 1) {
    int a = (t >= s) ? tmp[t - s] : 0;
    __syncthreads();
    tmp[t] += a;
    __syncthreads();
  }
  if (t < 391) part[t] = tmp[t] - v;   // exclusive
}

__global__ __launch_bounds__(256) void scan_fin(const int* __restrict__ deg,
                                                const int* __restrict__ part,
                                                int* __restrict__ row_ptr,
                                                int* __restrict__ cursor) {
  __shared__ int tmp[256];
  int i = blockIdx.x * 256 + threadIdx.x;
  int t = threadIdx.x;
  int v = (i < NN) ? deg[i] : 0;
  tmp[t] = v;
  __syncthreads();
  for (int s = 1; s < 256; s <<= 1) {
    int a = (t >= s) ? tmp[t - s] : 0;
    __syncthreads();
    tmp[t] += a;
    __syncthreads();
  }
  int excl = tmp[t] - v + part[blockIdx.x];
  if (i < NN) {
    row_ptr[i] = excl;
    cursor[i] = excl;
  }
  if (i == 0) row_ptr[NN] = EE;
}

__global__ __launch_bounds__(256) void scatter_ids(const int* __restrict__ src,
                                                   const int* __restrict__ dst,
                                                   int* __restrict__ cursor,
                                                   int* __restrict__ csr_src) {
  int e = blockIdx.x * 256 + threadIdx.x;
  if (e < EE) {
    int slot = atomicAdd(&cursor[dst[e]], 1);
    csr_src[slot] = src[e];
  }
}

// ---------- gather + mean (one wave per dst node, no feature atomics) ----------
__global__ __launch_bounds__(256) void gather_mean(
    const unsigned short* __restrict__ h2, const float* __restrict__ sc,
    const float* __restrict__ sh, const int* __restrict__ csr_src,
    const int* __restrict__ row_ptr, unsigned short* __restrict__ mean) {
  const int lane = threadIdx.x & 63;
  const int node = (blockIdx.x << 2) + (threadIdx.x >> 6);
  if (node >= NN) return;
  const int c0 = lane * 2;
  const float s0 = sc[c0], s1 = sc[c0 + 1], t0 = sh[c0], t1 = sh[c0 + 1];
  const int beg = row_ptr[node], end = row_ptr[node + 1];
  float a0 = 0.f, a1 = 0.f;
  for (int e = beg; e < end; ++e) {
    int sn = csr_src[e];
    unsigned u = *(const unsigned*)(h2 + sn * 128 + c0);
    a0 += fmaxf(b2f((unsigned short)u) * s0 + t0, 0.f);
    a1 += fmaxf(b2f((unsigned short)(u >> 16)) * s1 + t1, 0.f);
  }
  float rc = (end > beg) ? 1.f / (float)(end - beg) : 0.f;
  unsigned out = ((unsigned)f2b(a1 * rc) << 16) | (unsigned)f2b(a0 * rc);
  *(unsigned*)(mean + node * 128 + c0) = out;
}

// ---------- final normalize to fp32 output ----------
__global__ __launch_bounds__(256) void norm_out(
    const unsigned short* __restrict__ h, const float* __restrict__ sc,
    const float* __restrict__ sh, float* __restrict__ out) {
  int idx = blockIdx.x * 256 + threadIdx.x;
  int e = idx * 8;
  u16x8 v = *(const u16x8*)(h + e);
  int cb = e & 127;
  f32x4 sA = *(const f32x4*)(sc + cb), sB = *(const f32x4*)(sc + cb + 4);
  f32x4 tA = *(const f32x4*)(sh + cb), tB = *(const f32x4*)(sh + cb + 4);
  f32x4 o0, o1;
  o0.x = fmaxf(b2f(v[0]) * sA.x + tA.x, 0.f);
  o0.y = fmaxf(b2f(v[1]) * sA.y + tA.y, 0.f);
  o0.z = fmaxf(b2f(v[2]) * sA.z + tA.z, 0.f);
  o0.w = fmaxf(b2f(v[3]) * sA.w + tA.w, 0.f);
  o1.x = fmaxf(b2f(v[4]) * sB.x + tB.x, 0.f);
  o1.y = fmaxf(b2f(v[5]) * sB.y + tB.y, 0.f);
  o1.z = fmaxf(b2f(v[6]) * sB.z + tB.z, 0.f);
  o1.w = fmaxf(b2f(v[7]) * sB.w + tB.w, 0.f);
  *(f32x4*)(out + e) = o0;
  *(f32x4*)(out + e + 4) = o1;
}

extern "C" void kernel_launch(void* const* d_in, const int* in_sizes, int n_in,
                              void* d_out, int out_size, void* d_ws, size_t ws_size,
                              hipStream_t stream) {
  (void)in_sizes; (void)n_in; (void)out_size; (void)ws_size;
  const float* feat = (const float*)d_in[0];
  const int* src = (const int*)d_in[1];
  const int* dst = (const int*)d_in[2];
  const float* aW1 = (const float*)d_in[3];
  const float* aW2 = (const float*)d_in[4];
  const float* sW1 = (const float*)d_in[5];
  const float* sW2 = (const float*)d_in[6];
  const float* cW1 = (const float*)d_in[7];
  const float* cW2 = (const float*)d_in[8];
  // layer order: 0=aggr1 1=aggr2 2=self1 3=self2 4=comb1 5=comb2
  const float* g[6] = {(const float*)d_in[10], (const float*)d_in[13],
                       (const float*)d_in[16], (const float*)d_in[19],
                       (const float*)d_in[22], (const float*)d_in[25]};
  const float* be[6] = {(const float*)d_in[11], (const float*)d_in[14],
                        (const float*)d_in[17], (const float*)d_in[20],
                        (const float*)d_in[23], (const float*)d_in[26]};

  char* ws = (char*)d_ws;
  unsigned short* WA = (unsigned short*)ws;                    // 25.6 MB bf16 buffer A
  unsigned short* WB = (unsigned short*)(ws + 25600000);       // 25.6 MB bf16 buffer B
  int* row_ptr = (int*)(ws + 51200000);                        // 400,016 B (+pad)
  int* deg = (int*)(ws + 51600128);                            // 400,000 B
  float* stats = (float*)(ws + 52000128);                      // 12,288 B
  int* cursor = (int*)(ws + 52012416);                         // 400,000 B
  int* part = (int*)(ws + 52412416);                           // 2,048 B
  int* csr_src = (int*)(ws + 52414464);                        // 2,560,000 B
  unsigned short* wt = (unsigned short*)(ws + 54974464);       // 229,376 B
  float* outF = (float*)d_out;
  unsigned short* h4 = (unsigned short*)d_out;                 // park h4 (bf16) in d_out bytes

  float* CS[6]; float* CQ[6]; float* SC[6]; float* SH[6];
  for (int L = 0; L < 6; ++L) {
    CS[L] = stats + L * 512;
    CQ[L] = stats + L * 512 + 128;
    SC[L] = stats + L * 512 + 256;
    SH[L] = stats + L * 512 + 384;
  }

  hipMemsetAsync(ws + 51600128, 0, 412288, stream);            // deg + stats accumulators
  prep_wt<<<7, 256, 0, stream>>>(aW1, aW2, sW1, sW2, cW1, cW2, wt);

  // ---- CSR build (independent of GEMM chain) ----
  hist_deg<<<2500, 256, 0, stream>>>(dst, deg);
  scan_part<<<391, 256, 0, stream>>>(deg, part);
  scan_top<<<1, 512, 0, stream>>>(part);
  scan_fin<<<391, 256, 0, stream>>>(deg, part, row_ptr, cursor);
  scatter_ids<<<2500, 256, 0, stream>>>(src, dst, cursor, csr_src);

  dim3 gg(782);
  // L1: feat -> h1 (WA)
  gemm_bn<1, 0><<<gg, 256, 0, stream>>>(feat, nullptr, nullptr, nullptr,
                                        wt + 0 * 16384, WA, CS[0], CQ[0]);
  fin_stats<<<1, 128, 0, stream>>>(CS[0], CQ[0], g[0], be[0], SC[0], SH[0]);
  // L2: n(h1) -> h2 (WB)
  gemm_bn<1, 1><<<gg, 256, 0, stream>>>(WA, nullptr, SC[0], SH[0],
                                        wt + 1 * 16384, WB, CS[1], CQ[1]);
  fin_stats<<<1, 128, 0, stream>>>(CS[1], CQ[1], g[1], be[1], SC[1], SH[1]);
  // gather-mean of n(h2) into WA? no — WA holds h1 until L3 overwrites; use after L3 frees it.
  // Order: L3 first (reads feat, writes WA over dead h1), then gather into... WA is h3.
  // So gather writes its own slot: reuse WB after L5? No — simplest: gather -> csr-adjacent
  // region is too small; instead gather AFTER L4 into WA (h3 dead then).
  // L3: feat -> h3 (WA)
  gemm_bn<1, 0><<<gg, 256, 0, stream>>>(feat, nullptr, nullptr, nullptr,
                                        wt + 2 * 16384, WA, CS[2], CQ[2]);
  fin_stats<<<1, 128, 0, stream>>>(CS[2], CQ[2], g[2], be[2], SC[2], SH[2]);
  // L4: n(h3) -> h4 (d_out bytes)
  gemm_bn<1, 1><<<gg, 256, 0, stream>>>(WA, nullptr, SC[2], SH[2],
                                        wt + 3 * 16384, h4, CS[3], CQ[3]);
  fin_stats<<<1, 128, 0, stream>>>(CS[3], CQ[3], g[3], be[3], SC[3], SH[3]);
  // gather: mean of n(h2[src]) per dst -> WA (h3 dead, h1 dead)
  gather_mean<<<25000, 256, 0, stream>>>(WB, SC[1], SH[1], csr_src, row_ptr, WA);
  // L5: [n(h4) | mean] -> h5 (WB; h2 dead after gather)
  gemm_bn<2, 2><<<gg, 256, 0, stream>>>(h4, WA, SC[3], SH[3],
                                        wt + 4 * 16384, WB, CS[4], CQ[4]);
  fin_stats<<<1, 128, 0, stream>>>(CS[4], CQ[4], g[4], be[4], SC[4], SH[4]);
  // L6: n(h5) -> h6 (WA; mean dead after L5)
  gemm_bn<1, 1><<<gg, 256, 0, stream>>>(WB, nullptr, SC[4], SH[4],
                                        wt + 6 * 16384, WA, CS[5], CQ[5]);
  fin_stats<<<1, 128, 0, stream>>>(CS[5], CQ[5], g[5], be[5], SC[5], SH[5]);
  // final normalize -> fp32 out
  norm_out<<<6250, 256, 0, stream>>>(WA, SC[5], SH[5], outF);
}

// Round 3
// 391.553 us; speedup vs baseline: 2.3594x; 1.2748x over previous
//
#include <hip/hip_runtime.h>

#define NN 100000
#define EE 640000

typedef float f32x4 __attribute__((ext_vector_type(4)));
typedef __bf16 bf16x8 __attribute__((ext_vector_type(8)));
typedef unsigned short u16x4 __attribute__((ext_vector_type(4)));
typedef unsigned short u16x8 __attribute__((ext_vector_type(8)));

__device__ __forceinline__ unsigned short f2b(float f) {
  unsigned u = __float_as_uint(f);
  u += 0x7fffu + ((u >> 16) & 1u);   // RNE; inputs finite
  return (unsigned short)(u >> 16);
}
__device__ __forceinline__ float b2f(unsigned short h) {
  return __uint_as_float(((unsigned)h) << 16);
}
__device__ __forceinline__ void gl2lds(const void* g, void* l) {
  __builtin_amdgcn_global_load_lds((const __attribute__((address_space(1))) void*)g,
                                   (__attribute__((address_space(3))) void*)l, 16, 0, 0);
}

// ---------- weights: transpose + XOR-swizzle + bf16 (7 chunks of 128x128) ----------
__global__ __launch_bounds__(256) void prep_wt(
    const float* __restrict__ w0, const float* __restrict__ w1,
    const float* __restrict__ w2, const float* __restrict__ w3,
    const float* __restrict__ w4, const float* __restrict__ w5,
    unsigned short* __restrict__ wt) {
  int chunk = blockIdx.x >> 4, sub = blockIdx.x & 15;
  const float* W; int kc = 0;
  switch (chunk) {
    case 0: W = w0; break;
    case 1: W = w1; break;
    case 2: W = w2; break;
    case 3: W = w3; break;
    case 4: W = w4; break;
    case 5: W = w4; kc = 128; break;
    default: W = w5; break;
  }
  unsigned short* out = wt + chunk * 16384;
#pragma unroll
  for (int p = 0; p < 4; ++p) {
    int idx = sub * 1024 + p * 256 + threadIdx.x;
    int k = idx >> 7, c = idx & 127;
    out[c * 128 + (((k >> 3) ^ (c & 7)) << 3) + (k & 7)] = f2b(W[(kc + k) * 128 + c]);
  }
}

// ---------- feat fp32 -> bf16 in tile-swizzled (LDS-image) layout ----------
__global__ __launch_bounds__(256) void featconv(const float* __restrict__ feat,
                                                unsigned short* __restrict__ fsw) {
  const int t = blockIdx.x, tid = threadIdx.x;
#pragma unroll
  for (int p = 0; p < 8; ++p) {
    int u = p * 256 + tid;
    int r = u >> 4, kk = u & 15;
    int grow = t * 128 + r;
    int c8 = (kk ^ (r & 7)) << 3;
    u16x8 o = {};
    if (grow < NN) {
      f32x4 a = *(const f32x4*)(feat + (size_t)grow * 128 + c8);
      f32x4 b = *(const f32x4*)(feat + (size_t)grow * 128 + c8 + 4);
      o[0] = f2b(a.x); o[1] = f2b(a.y); o[2] = f2b(a.z); o[3] = f2b(a.w);
      o[4] = f2b(b.x); o[5] = f2b(b.y); o[6] = f2b(b.z); o[7] = f2b(b.w);
    }
    *(u16x8*)(fsw + (size_t)t * 16384 + (size_t)u * 8) = o;
  }
}

// ---------- shared epilogue: BN-stat partials + row-major bf16 store ----------
__device__ __forceinline__ void epi_store(const f32x4 (&acc)[4][4], int row0, int wm, int wn,
                                          int lane, unsigned short* __restrict__ H,
                                          float* __restrict__ colsum,
                                          float* __restrict__ colsumsq) {
  float s[4] = {0.f, 0.f, 0.f, 0.f}, q[4] = {0.f, 0.f, 0.f, 0.f};
#pragma unroll
  for (int n = 0; n < 4; ++n)
#pragma unroll
    for (int m = 0; m < 4; ++m)
#pragma unroll
      for (int i = 0; i < 4; ++i) {
        float v = acc[m][n][i];
        s[n] += v;
        q[n] += v * v;
      }
#pragma unroll
  for (int n = 0; n < 4; ++n) {
    s[n] += __shfl_xor(s[n], 16);
    s[n] += __shfl_xor(s[n], 32);
    q[n] += __shfl_xor(q[n], 16);
    q[n] += __shfl_xor(q[n], 32);
  }
  if ((lane >> 4) == 0) {
#pragma unroll
    for (int n = 0; n < 4; ++n) {
      unsafeAtomicAdd(&colsum[wn + n * 16 + lane], s[n]);
      unsafeAtomicAdd(&colsumsq[wn + n * 16 + lane], q[n]);
    }
  }
  const int rg = lane >> 4, c = lane & 15;
#pragma unroll
  for (int m = 0; m < 4; ++m)
#pragma unroll
    for (int i = 0; i < 4; ++i) {
      int row = row0 + wm + m * 16 + rg * 4 + i;
      if (row < NN) {
#pragma unroll
        for (int n = 0; n < 4; ++n)
          H[(size_t)row * 128 + wn + n * 16 + c] = f2b(acc[m][n][i]);
      }
    }
}

// ---------- dual GEMM: L1 + L3 share A = feat (swizzled bf16), W direct-from-L2 ----------
__global__ __launch_bounds__(256, 2) void gemm_dual(
    const unsigned short* __restrict__ fsw,
    const unsigned short* __restrict__ Wt0, const unsigned short* __restrict__ Wt2,
    unsigned short* __restrict__ H1, unsigned short* __restrict__ H3,
    float* __restrict__ cs0, float* __restrict__ cq0,
    float* __restrict__ cs2, float* __restrict__ cq2) {
  __shared__ unsigned short Alds[16384];
  const int tid = threadIdx.x;
  const int lane = tid & 63, wid = tid >> 6;
  const int row0 = blockIdx.x * 128;
  const int wm = (wid >> 1) * 64, wn = (wid & 1) * 64;
#pragma unroll
  for (int j = 0; j < 8; ++j) {
    int u = (wid * 8 + j) * 64 + lane;
    gl2lds(fsw + (size_t)blockIdx.x * 16384 + (size_t)u * 8, &Alds[(wid * 8 + j) * 512]);
  }
  __syncthreads();
  f32x4 accA[4][4] = {}, accB[4][4] = {};
#pragma unroll
  for (int ks = 0; ks < 4; ++ks) {
    const int kg = ks * 4 + (lane >> 4);
    bf16x8 af[4], b0[4], b2[4];
#pragma unroll
    for (int m = 0; m < 4; ++m) {
      int rr = wm + m * 16 + (lane & 15);
      af[m] = *(const bf16x8*)&Alds[rr * 128 + ((kg ^ (rr & 7)) << 3)];
    }
#pragma unroll
    for (int n = 0; n < 4; ++n) {
      int cc = wn + n * 16 + (lane & 15);
      int off = cc * 128 + ((kg ^ (cc & 7)) << 3);
      b0[n] = *(const bf16x8*)(Wt0 + off);
      b2[n] = *(const bf16x8*)(Wt2 + off);
    }
#pragma unroll
    for (int m = 0; m < 4; ++m)
#pragma unroll
      for (int n = 0; n < 4; ++n) {
        accA[m][n] = __builtin_amdgcn_mfma_f32_16x16x32_bf16(af[m], b0[n], accA[m][n], 0, 0, 0);
        accB[m][n] = __builtin_amdgcn_mfma_f32_16x16x32_bf16(af[m], b2[n], accB[m][n], 0, 0, 0);
      }
  }
  epi_store(accA, row0, wm, wn, lane, H1, cs0, cq0);
  epi_store(accB, row0, wm, wn, lane, H3, cs2, cq2);
}

// ---------- single GEMM, fused input-BN (inline stats), W direct-from-L2 ----------
// MODE 1 (NCHK=1): A = bf16 h row-major, transform relu(h*sc+sh)
// MODE 2 (NCHK=2): ch0 = transform on Aptr; ch1 = raw swizzled bf16 via global_load_lds
template <int NCHK, int MODE>
__global__ __launch_bounds__(256, 3) void gemm_bn(
    const unsigned short* __restrict__ Aptr, const unsigned short* __restrict__ A2sw,
    const float* __restrict__ csIn, const float* __restrict__ cqIn,
    const float* __restrict__ g, const float* __restrict__ beta,
    const unsigned short* __restrict__ Wt, unsigned short* __restrict__ Hout,
    float* __restrict__ colsum, float* __restrict__ colsumsq) {
  __shared__ unsigned short Alds[16384];
  __shared__ float scs[128], shs[128];
  const int tid = threadIdx.x;
  if (tid < 128) {
    float mu = csIn[tid] * (1.f / NN);
    float var = cqIn[tid] * (1.f / NN) - mu * mu;
    float s = g[tid] * rsqrtf(fmaxf(var, 0.f) + 1e-5f);
    scs[tid] = s;
    shs[tid] = beta[tid] - mu * s;
  }
  __syncthreads();
  const int lane = tid & 63, wid = tid >> 6;
  const int row0 = blockIdx.x * 128;
  const int wm = (wid >> 1) * 64, wn = (wid & 1) * 64;
  const int r8 = tid >> 5;
  const int kq = (tid & 31) * 4;
  const f32x4 scv = *(const f32x4*)&scs[kq];
  const f32x4 shv = *(const f32x4*)&shs[kq];

  f32x4 acc[4][4] = {};
#pragma unroll
  for (int ch = 0; ch < NCHK; ++ch) {
    if (ch) __syncthreads();
    if (MODE == 2 && ch == 1) {
#pragma unroll
      for (int j = 0; j < 8; ++j) {
        int u = (wid * 8 + j) * 64 + lane;
        gl2lds(A2sw + (size_t)blockIdx.x * 16384 + (size_t)u * 8, &Alds[(wid * 8 + j) * 512]);
      }
    } else {
      u16x4 raw[16];
      const u16x4 zz = {};
#pragma unroll
      for (int it = 0; it < 16; ++it) {
        int grow = row0 + it * 8 + r8;
        raw[it] = (grow < NN) ? *(const u16x4*)(Aptr + (size_t)grow * 128 + kq) : zz;
      }
#pragma unroll
      for (int it = 0; it < 16; ++it) {
        int r = it * 8 + r8;
        bool ok = (row0 + r) < NN;
        float v0 = fmaxf(b2f(raw[it].x) * scv.x + shv.x, 0.f);
        float v1 = fmaxf(b2f(raw[it].y) * scv.y + shv.y, 0.f);
        float v2 = fmaxf(b2f(raw[it].z) * scv.z + shv.z, 0.f);
        float v3 = fmaxf(b2f(raw[it].w) * scv.w + shv.w, 0.f);
        u16x4 p;
        p.x = ok ? f2b(v0) : (unsigned short)0;
        p.y = ok ? f2b(v1) : (unsigned short)0;
        p.z = ok ? f2b(v2) : (unsigned short)0;
        p.w = ok ? f2b(v3) : (unsigned short)0;
        *(u16x4*)&Alds[r * 128 + (((kq >> 3) ^ (r & 7)) << 3) + (kq & 7)] = p;
      }
    }
    __syncthreads();
    const unsigned short* wsrc = Wt + ch * 16384;
#pragma unroll
    for (int ks = 0; ks < 4; ++ks) {
      const int kg = ks * 4 + (lane >> 4);
      bf16x8 af[4], bfr[4];
#pragma unroll
      for (int m = 0; m < 4; ++m) {
        int rr = wm + m * 16 + (lane & 15);
        af[m] = *(const bf16x8*)&Alds[rr * 128 + ((kg ^ (rr & 7)) << 3)];
      }
#pragma unroll
      for (int n = 0; n < 4; ++n) {
        int cc = wn + n * 16 + (lane & 15);
        bfr[n] = *(const bf16x8*)(wsrc + cc * 128 + ((kg ^ (cc & 7)) << 3));
      }
#pragma unroll
      for (int m = 0; m < 4; ++m)
#pragma unroll
        for (int n = 0; n < 4; ++n)
          acc[m][n] = __builtin_amdgcn_mfma_f32_16x16x32_bf16(af[m], bfr[n], acc[m][n], 0, 0, 0);
    }
  }
  epi_store(acc, row0, wm, wn, lane, Hout, colsum, colsumsq);
}

// ---------- CSR build ----------
__global__ __launch_bounds__(256) void hist_slot(const int* __restrict__ dst,
                                                 int* __restrict__ deg, int* __restrict__ slot) {
  int e = blockIdx.x * 256 + threadIdx.x;
  if (e < EE) slot[e] = atomicAdd(&deg[dst[e]], 1);
}

__global__ __launch_bounds__(256) void scan_part(const int* __restrict__ deg,
                                                 int* __restrict__ part) {
  __shared__ int tmp[256];
  int i = blockIdx.x * 256 + threadIdx.x;
  int t = threadIdx.x;
  tmp[t] = (i < NN) ? deg[i] : 0;
  __syncthreads();
  for (int s = 128; s > 0; s >>= 1) {
    if (t < s) tmp[t] += tmp[t + s];
    __syncthreads();
  }
  if (t == 0) part[blockIdx.x] = tmp[0];
}

__global__ __launch_bounds__(512) void scan_top(int* __restrict__ part) {
  __shared__ int tmp[512];
  int t = threadIdx.x;
  int v = (t < 391) ? part[t] : 0;
  tmp[t] = v;
  __syncthreads();
  for (int s = 1; s < 512; s <<= 1) {
    int a = (t >= s) ? tmp[t - s] : 0;
    __syncthreads();
    tmp[t] += a;
    __syncthreads();
  }
  if (t < 391) part[t] = tmp[t] - v;   // exclusive
}

__global__ __launch_bounds__(256) void scan_fin(const int* __restrict__ deg,
                                                const int* __restrict__ part,
                                                int* __restrict__ row_ptr) {
  __shared__ int tmp[256];
  int i = blockIdx.x * 256 + threadIdx.x;
  int t = threadIdx.x;
  int v = (i < NN) ? deg[i] : 0;
  tmp[t] = v;
  __syncthreads();
  for (int s = 1; s < 256; s <<= 1) {
    int a = (t >= s) ? tmp[t - s] : 0;
    __syncthreads();
    tmp[t] += a;
    __syncthreads();
  }
  if (i < NN) row_ptr[i] = tmp[t] - v + part[blockIdx.x];
  if (i == 0) row_ptr[NN] = EE;
}

__global__ __launch_bounds__(256) void scatter_ids(const int* __restrict__ src,
                                                   const int* __restrict__ dst,
                                                   const int* __restrict__ row_ptr,
                                                   const int* __restrict__ slot,
                                                   int* __restrict__ csr_src) {
  int e = blockIdx.x * 256 + threadIdx.x;
  if (e < EE) csr_src[row_ptr[dst[e]] + slot[e]] = src[e];
}

// ---------- gather + mean: one wave/node, 4-deep pipelined, swizzled output ----------
__global__ __launch_bounds__(256) void gather_mean(
    const unsigned short* __restrict__ h2, const float* __restrict__ csIn,
    const float* __restrict__ cqIn, const float* __restrict__ g,
    const float* __restrict__ beta, const int* __restrict__ csr_src,
    const int* __restrict__ row_ptr, unsigned short* __restrict__ mean_sw) {
  const int lane = threadIdx.x & 63;
  const int node = (blockIdx.x << 2) + (threadIdx.x >> 6);
  if (node >= 100096) return;
  const int c0 = lane * 2;
  float mu0 = csIn[c0] * (1.f / NN), mu1 = csIn[c0 + 1] * (1.f / NN);
  float va0 = cqIn[c0] * (1.f / NN) - mu0 * mu0, va1 = cqIn[c0 + 1] * (1.f / NN) - mu1 * mu1;
  float s0 = g[c0] * rsqrtf(fmaxf(va0, 0.f) + 1e-5f);
  float s1 = g[c0 + 1] * rsqrtf(fmaxf(va1, 0.f) + 1e-5f);
  float t0 = beta[c0] - mu0 * s0, t1 = beta[c0 + 1] - mu1 * s1;
  float a0 = 0.f, a1 = 0.f, rc = 0.f;
  if (node < NN) {
    const int beg = row_ptr[node], end = row_ptr[node + 1];
    int e = beg;
    for (; e + 4 <= end; e += 4) {
      int n0 = csr_src[e], n1 = csr_src[e + 1], n2 = csr_src[e + 2], n3 = csr_src[e + 3];
      unsigned u0 = *(const unsigned*)(h2 + (size_t)n0 * 128 + c0);
      unsigned u1 = *(const unsigned*)(h2 + (size_t)n1 * 128 + c0);
      unsigned u2 = *(const unsigned*)(h2 + (size_t)n2 * 128 + c0);
      unsigned u3 = *(const unsigned*)(h2 + (size_t)n3 * 128 + c0);
      a0 += fmaxf(b2f((unsigned short)u0) * s0 + t0, 0.f);
      a1 += fmaxf(b2f((unsigned short)(u0 >> 16)) * s1 + t1, 0.f);
      a0 += fmaxf(b2f((unsigned short)u1) * s0 + t0, 0.f);
      a1 += fmaxf(b2f((unsigned short)(u1 >> 16)) * s1 + t1, 0.f);
      a0 += fmaxf(b2f((unsigned short)u2) * s0 + t0, 0.f);
      a1 += fmaxf(b2f((unsigned short)(u2 >> 16)) * s1 + t1, 0.f);
      a0 += fmaxf(b2f((unsigned short)u3) * s0 + t0, 0.f);
      a1 += fmaxf(b2f((unsigned short)(u3 >> 16)) * s1 + t1, 0.f);
    }
    if (e + 2 <= end) {
      int n0 = csr_src[e], n1 = csr_src[e + 1];
      unsigned u0 = *(const unsigned*)(h2 + (size_t)n0 * 128 + c0);
      unsigned u1 = *(const unsigned*)(h2 + (size_t)n1 * 128 + c0);
      a0 += fmaxf(b2f((unsigned short)u0) * s0 + t0, 0.f);
      a1 += fmaxf(b2f((unsigned short)(u0 >> 16)) * s1 + t1, 0.f);
      a0 += fmaxf(b2f((unsigned short)u1) * s0 + t0, 0.f);
      a1 += fmaxf(b2f((unsigned short)(u1 >> 16)) * s1 + t1, 0.f);
      e += 2;
    }
    if (e < end) {
      int n0 = csr_src[e];
      unsigned u0 = *(const unsigned*)(h2 + (size_t)n0 * 128 + c0);
      a0 += fmaxf(b2f((unsigned short)u0) * s0 + t0, 0.f);
      a1 += fmaxf(b2f((unsigned short)(u0 >> 16)) * s1 + t1, 0.f);
    }
    int d = end - beg;
    rc = (d > 0) ? 1.f / (float)d : 0.f;
  }
  // swizzled write: tile t, row r, unit kk, byte slot (lane&3)
  int r = node & 127, t = node >> 7;
  int kk = (lane >> 2) ^ (r & 7);
  unsigned out = ((unsigned)f2b(a1 * rc) << 16) | (unsigned)f2b(a0 * rc);
  *(unsigned*)(mean_sw + (size_t)(t * 2048 + r * 16 + kk) * 8 + (lane & 3) * 2) = out;
}

// ---------- final normalize -> fp32 out (inline stats) ----------
__global__ __launch_bounds__(256) void norm_out(
    const unsigned short* __restrict__ h, const float* __restrict__ csIn,
    const float* __restrict__ cqIn, const float* __restrict__ g,
    const float* __restrict__ beta, float* __restrict__ out) {
  __shared__ float scs[128], shs[128];
  const int tid = threadIdx.x;
  if (tid < 128) {
    float mu = csIn[tid] * (1.f / NN);
    float var = cqIn[tid] * (1.f / NN) - mu * mu;
    float s = g[tid] * rsqrtf(fmaxf(var, 0.f) + 1e-5f);
    scs[tid] = s;
    shs[tid] = beta[tid] - mu * s;
  }
  __syncthreads();
  size_t e = ((size_t)blockIdx.x * 256 + tid) * 8;
  u16x8 v = *(const u16x8*)(h + e);
  int cb = (int)(e & 127);
  f32x4 sA = *(const f32x4*)&scs[cb], sB = *(const f32x4*)&scs[cb + 4];
  f32x4 tA = *(const f32x4*)&shs[cb], tB = *(const f32x4*)&shs[cb + 4];
  f32x4 o0, o1;
  o0.x = fmaxf(b2f(v[0]) * sA.x + tA.x, 0.f);
  o0.y = fmaxf(b2f(v[1]) * sA.y + tA.y, 0.f);
  o0.z = fmaxf(b2f(v[2]) * sA.z + tA.z, 0.f);
  o0.w = fmaxf(b2f(v[3]) * sA.w + tA.w, 0.f);
  o1.x = fmaxf(b2f(v[4]) * sB.x + tB.x, 0.f);
  o1.y = fmaxf(b2f(v[5]) * sB.y + tB.y, 0.f);
  o1.z = fmaxf(b2f(v[6]) * sB.z + tB.z, 0.f);
  o1.w = fmaxf(b2f(v[7]) * sB.w + tB.w, 0.f);
  *(f32x4*)(out + e) = o0;
  *(f32x4*)(out + e + 4) = o1;
}

extern "C" void kernel_launch(void* const* d_in, const int* in_sizes, int n_in,
                              void* d_out, int out_size, void* d_ws, size_t ws_size,
                              hipStream_t stream) {
  (void)in_sizes; (void)n_in; (void)out_size; (void)ws_size;
  const float* feat = (const float*)d_in[0];
  const int* src = (const int*)d_in[1];
  const int* dst = (const int*)d_in[2];
  const float* aW1 = (const float*)d_in[3];
  const float* aW2 = (const float*)d_in[4];
  const float* sW1 = (const float*)d_in[5];
  const float* sW2 = (const float*)d_in[6];
  const float* cW1 = (const float*)d_in[7];
  const float* cW2 = (const float*)d_in[8];
  // layer order: 0=aggr1 1=aggr2 2=self1 3=self2 4=comb1 5=comb2
  const float* g[6] = {(const float*)d_in[10], (const float*)d_in[13],
                       (const float*)d_in[16], (const float*)d_in[19],
                       (const float*)d_in[22], (const float*)d_in[25]};
  const float* be[6] = {(const float*)d_in[11], (const float*)d_in[14],
                        (const float*)d_in[17], (const float*)d_in[20],
                        (const float*)d_in[23], (const float*)d_in[26]};

  char* ws = (char*)d_ws;
  const size_t S = 25624576;                                   // 782 tiles * 32768 B
  unsigned short* WA = (unsigned short*)ws;                    // h1 / mean_sw
  unsigned short* WB = (unsigned short*)(ws + S);              // h2 / h6
  unsigned short* WC = (unsigned short*)(ws + 2 * S);          // h3 / h5
  int* row_ptr = (int*)(ws + 76873728);                        // 400,128 B
  int* deg = (int*)(ws + 77273856);                            // 400,000 B
  float* stats = (float*)(ws + 77673856);                      // 12,288 B
  int* slot = (int*)(ws + 77686144);                           // 2,560,000 B
  int* part = (int*)(ws + 80246144);                           // 2,048 B
  int* csr_src = (int*)(ws + 80248192);                        // 2,560,000 B
  unsigned short* wt = (unsigned short*)(ws + 82808192);       // 229,376 B
  float* outF = (float*)d_out;
  unsigned short* fsw = (unsigned short*)d_out;                // swizzled bf16 feat (first 25.6 MB)
  unsigned short* h4 = (unsigned short*)((char*)d_out + 25600000);  // h4 row-major (second half)

  float* CS[6]; float* CQ[6];
  for (int L = 0; L < 6; ++L) {
    CS[L] = stats + L * 512;
    CQ[L] = stats + L * 512 + 128;
  }

  hipMemsetAsync(deg, 0, 412288, stream);                      // deg + stats accumulators
  featconv<<<782, 256, 0, stream>>>(feat, fsw);
  prep_wt<<<112, 256, 0, stream>>>(aW1, aW2, sW1, sW2, cW1, cW2, wt);

  // CSR build
  hist_slot<<<2500, 256, 0, stream>>>(dst, deg, slot);
  scan_part<<<391, 256, 0, stream>>>(deg, part);
  scan_top<<<1, 512, 0, stream>>>(part);
  scan_fin<<<391, 256, 0, stream>>>(deg, part, row_ptr);
  scatter_ids<<<2500, 256, 0, stream>>>(src, dst, row_ptr, slot, csr_src);

  dim3 gg(782);
  // L1 + L3 fused: feat -> h1 (WA), h3 (WC)
  gemm_dual<<<gg, 256, 0, stream>>>(fsw, wt + 0 * 16384, wt + 2 * 16384,
                                    WA, WC, CS[0], CQ[0], CS[2], CQ[2]);
  // L2: n(h1) -> h2 (WB)
  gemm_bn<1, 1><<<gg, 256, 0, stream>>>(WA, nullptr, CS[0], CQ[0], g[0], be[0],
                                        wt + 1 * 16384, WB, CS[1], CQ[1]);
  // L4: n(h3) -> h4 (d_out second half)
  gemm_bn<1, 1><<<gg, 256, 0, stream>>>(WC, nullptr, CS[2], CQ[2], g[2], be[2],
                                        wt + 3 * 16384, h4, CS[3], CQ[3]);
  // gather: mean of n(h2[src]) per dst -> WA (swizzled; h1 dead)
  gather_mean<<<25024, 256, 0, stream>>>(WB, CS[1], CQ[1], g[1], be[1],
                                         csr_src, row_ptr, WA);
  // L5: [n(h4) | mean] -> h5 (WC; h3 dead)
  gemm_bn<2, 2><<<gg, 256, 0, stream>>>(h4, WA, CS[3], CQ[3], g[3], be[3],
                                        wt + 4 * 16384, WC, CS[4], CQ[4]);
  // L6: n(h5) -> h6 (WB; h2 dead)
  gemm_bn<1, 1><<<gg, 256, 0, stream>>>(WC, nullptr, CS[4], CQ[4], g[4], be[4],
                                        wt + 6 * 16384, WB, CS[5], CQ[5]);
  // final normalize -> fp32 out
  norm_out<<<6250, 256, 0, stream>>>(WB, CS[5], CQ[5], g[5], be[5], outF);
}

// Round 5
// 279.430 us; speedup vs baseline: 3.3062x; 1.4013x over previous
//
#include <hip/hip_runtime.h>

#define NN 100000
#define EE 640000

typedef float f32x4 __attribute__((ext_vector_type(4)));
typedef __bf16 bf16x8 __attribute__((ext_vector_type(8)));
typedef unsigned short u16x4 __attribute__((ext_vector_type(4)));
typedef unsigned short u16x8 __attribute__((ext_vector_type(8)));

__device__ __forceinline__ unsigned short f2b(float f) {
  unsigned u = __float_as_uint(f);
  u += 0x7fffu + ((u >> 16) & 1u);   // RNE; inputs finite
  return (unsigned short)(u >> 16);
}
__device__ __forceinline__ float b2f(unsigned short h) {
  return __uint_as_float(((unsigned)h) << 16);
}
__device__ __forceinline__ void gl2lds(const void* g, void* l) {
  __builtin_amdgcn_global_load_lds((const __attribute__((address_space(1))) void*)g,
                                   (__attribute__((address_space(3))) void*)l, 16, 0, 0);
}

// ---------- weights: transpose + XOR-swizzle + bf16 (7 chunks of 128x128) ----------
__global__ __launch_bounds__(256) void prep_wt(
    const float* __restrict__ w0, const float* __restrict__ w1,
    const float* __restrict__ w2, const float* __restrict__ w3,
    const float* __restrict__ w4, const float* __restrict__ w5,
    unsigned short* __restrict__ wt) {
  int chunk = blockIdx.x >> 4, sub = blockIdx.x & 15;
  const float* W; int kc = 0;
  switch (chunk) {
    case 0: W = w0; break;
    case 1: W = w1; break;
    case 2: W = w2; break;
    case 3: W = w3; break;
    case 4: W = w4; break;
    case 5: W = w4; kc = 128; break;
    default: W = w5; break;
  }
  unsigned short* out = wt + chunk * 16384;
#pragma unroll
  for (int p = 0; p < 4; ++p) {
    int idx = sub * 1024 + p * 256 + threadIdx.x;
    int k = idx >> 7, c = idx & 127;
    out[c * 128 + (((k >> 3) ^ (c & 7)) << 3) + (k & 7)] = f2b(W[(kc + k) * 128 + c]);
  }
}

// ---------- unified GEMM: 512 thr, 8 waves (32x64 each), batched via blockIdx.y ----------
// MODE 0: A = fp32 raw (feat)
// MODE 1: A = bf16 row-major, transform relu(h*sc+sh); sc/sh from raw stats inline
// MODE 2: NCHK=2: ch0 = MODE1 transform on A; ch1 = swizzled bf16 (A2sw) via global_load_lds
struct GArg {
  const void* A;
  const unsigned short* A2sw;
  const float* cs; const float* cq; const float* g; const float* be;
  const unsigned short* W;
  unsigned short* H;
  float* ocs; float* ocq;
};

template <int NCHK, int MODE>
__global__ __launch_bounds__(512, 4) void gemm_bn(GArg pa, GArg pb) {
  const GArg P = blockIdx.y ? pb : pa;
  __shared__ unsigned short Alds[16384];    // 32 KB, full 128x128 bf16 swizzled A tile
  __shared__ unsigned short Epi[20480];     // 40 KB, per-wave 32x80 transpose pad
  __shared__ float Sred[1024];              // 4 KB, stats partials
  __shared__ float scs[128], shs[128];

  const int tid = threadIdx.x;
  if (MODE != 0) {
    if (tid < 128) {
      float mu = P.cs[tid] * (1.f / NN);
      float var = P.cq[tid] * (1.f / NN) - mu * mu;
      float s = P.g[tid] * rsqrtf(fmaxf(var, 0.f) + 1e-5f);
      scs[tid] = s;
      shs[tid] = P.be[tid] - mu * s;
    }
    __syncthreads();
  }
  const int lane = tid & 63, wid = tid >> 6;
  const int row0 = blockIdx.x * 128;
  const int wm = (wid >> 1) * 32, wn = (wid & 1) * 64;
  const int kq = (tid & 31) * 4;
  const int rbase = tid >> 5;               // 0..15
  f32x4 scv = {}, shv = {};
  if (MODE != 0) {
    scv = *(const f32x4*)&scs[kq];
    shv = *(const f32x4*)&shs[kq];
  }

  f32x4 acc[2][4] = {};
#pragma unroll
  for (int ch = 0; ch < NCHK; ++ch) {
    if (ch) __syncthreads();
    if (MODE == 2 && ch == 1) {
#pragma unroll
      for (int j = 0; j < 4; ++j) {
        int u = (wid * 4 + j) * 64 + lane;
        gl2lds(P.A2sw + (size_t)blockIdx.x * 16384 + (size_t)u * 8,
               &Alds[(wid * 4 + j) * 512]);
      }
    } else if (MODE == 0) {
      f32x4 raw[8];
      const f32x4 zz = {};
#pragma unroll
      for (int it = 0; it < 8; ++it) {
        int grow = row0 + it * 16 + rbase;
        raw[it] = (grow < NN) ? *(const f32x4*)((const float*)P.A + (size_t)grow * 128 + kq) : zz;
      }
#pragma unroll
      for (int it = 0; it < 8; ++it) {
        int r = it * 16 + rbase;
        u16x4 p;
        p.x = f2b(raw[it].x); p.y = f2b(raw[it].y);
        p.z = f2b(raw[it].z); p.w = f2b(raw[it].w);
        *(u16x4*)&Alds[r * 128 + (((kq >> 3) ^ (r & 7)) << 3) + (kq & 7)] = p;
      }
    } else {
      u16x4 raw[8];
      const u16x4 zz = {};
#pragma unroll
      for (int it = 0; it < 8; ++it) {
        int grow = row0 + it * 16 + rbase;
        raw[it] = (grow < NN) ? *(const u16x4*)((const unsigned short*)P.A + (size_t)grow * 128 + kq)
                              : zz;
      }
#pragma unroll
      for (int it = 0; it < 8; ++it) {
        int r = it * 16 + rbase;
        bool ok = (row0 + r) < NN;
        float v0 = fmaxf(b2f(raw[it].x) * scv.x + shv.x, 0.f);
        float v1 = fmaxf(b2f(raw[it].y) * scv.y + shv.y, 0.f);
        float v2 = fmaxf(b2f(raw[it].z) * scv.z + shv.z, 0.f);
        float v3 = fmaxf(b2f(raw[it].w) * scv.w + shv.w, 0.f);
        u16x4 p;
        p.x = ok ? f2b(v0) : (unsigned short)0;
        p.y = ok ? f2b(v1) : (unsigned short)0;
        p.z = ok ? f2b(v2) : (unsigned short)0;
        p.w = ok ? f2b(v3) : (unsigned short)0;
        *(u16x4*)&Alds[r * 128 + (((kq >> 3) ^ (r & 7)) << 3) + (kq & 7)] = p;
      }
    }
    __syncthreads();
    const unsigned short* wsrc = P.W + ch * 16384;
#pragma unroll
    for (int ks = 0; ks < 4; ++ks) {
      const int kg = ks * 4 + (lane >> 4);
      bf16x8 af[2], bfr[4];
#pragma unroll
      for (int m = 0; m < 2; ++m) {
        int rr = wm + m * 16 + (lane & 15);
        af[m] = *(const bf16x8*)&Alds[rr * 128 + ((kg ^ (rr & 7)) << 3)];
      }
#pragma unroll
      for (int n = 0; n < 4; ++n) {
        int cc = wn + n * 16 + (lane & 15);
        bfr[n] = *(const bf16x8*)(wsrc + cc * 128 + ((kg ^ (cc & 7)) << 3));
      }
#pragma unroll
      for (int m = 0; m < 2; ++m)
#pragma unroll
        for (int n = 0; n < 4; ++n)
          acc[m][n] = __builtin_amdgcn_mfma_f32_16x16x32_bf16(af[m], bfr[n], acc[m][n], 0, 0, 0);
    }
  }

  // ---- per-wave stats partials -> LDS ----
  {
    float s[4] = {0.f, 0.f, 0.f, 0.f}, q[4] = {0.f, 0.f, 0.f, 0.f};
#pragma unroll
    for (int n = 0; n < 4; ++n)
#pragma unroll
      for (int m = 0; m < 2; ++m)
#pragma unroll
        for (int i = 0; i < 4; ++i) {
          float v = acc[m][n][i];
          s[n] += v;
          q[n] += v * v;
        }
#pragma unroll
    for (int n = 0; n < 4; ++n) {
      s[n] += __shfl_xor(s[n], 16);
      s[n] += __shfl_xor(s[n], 32);
      q[n] += __shfl_xor(q[n], 16);
      q[n] += __shfl_xor(q[n], 32);
    }
    if ((lane >> 4) == 0) {
      int mg = wid >> 1;
#pragma unroll
      for (int n = 0; n < 4; ++n) {
        Sred[mg * 128 + wn + n * 16 + lane] = s[n];
        Sred[512 + mg * 128 + wn + n * 16 + lane] = q[n];
      }
    }
  }

  // ---- per-wave LDS transpose -> coalesced dwordx4 stores ----
  {
    unsigned short* ep = &Epi[wid * 2560];
#pragma unroll
    for (int m = 0; m < 2; ++m)
#pragma unroll
      for (int n = 0; n < 4; ++n)
#pragma unroll
        for (int i = 0; i < 4; ++i) {
          int wrow = m * 16 + (lane >> 4) * 4 + i;
          ep[wrow * 80 + n * 16 + (lane & 15)] = f2b(acc[m][n][i]);
        }
#pragma unroll
    for (int i4 = 0; i4 < 4; ++i4) {
      int wrow = i4 * 8 + (lane >> 3);
      u16x8 v = *(const u16x8*)&ep[wrow * 80 + (lane & 7) * 8];
      int R = row0 + wm + wrow;
      if (R < NN) *(u16x8*)&P.H[(size_t)R * 128 + wn + (lane & 7) * 8] = v;
    }
  }
  __syncthreads();
  // ---- block-level stats reduce: one atomic per col per block ----
  if (tid < 256) {
    int col = tid & 127;
    const float* sp = &Sred[(tid < 128) ? 0 : 512];
    float v = sp[col] + sp[128 + col] + sp[256 + col] + sp[384 + col];
    unsafeAtomicAdd(((tid < 128) ? P.ocs : P.ocq) + col, v);
  }
}

// ---------- CSR build ----------
__global__ __launch_bounds__(256) void hist_slot(const int* __restrict__ dst,
                                                 int* __restrict__ deg, int* __restrict__ slot) {
  int e = blockIdx.x * 256 + threadIdx.x;
  if (e < EE) slot[e] = atomicAdd(&deg[dst[e]], 1);
}

__global__ __launch_bounds__(256) void scan_part(const int* __restrict__ deg,
                                                 int* __restrict__ part) {
  __shared__ int tmp[256];
  int i = blockIdx.x * 256 + threadIdx.x;
  int t = threadIdx.x;
  tmp[t] = (i < NN) ? deg[i] : 0;
  __syncthreads();
  for (int s = 128; s > 0; s >>= 1) {
    if (t < s) tmp[t] += tmp[t + s];
    __syncthreads();
  }
  if (t == 0) part[blockIdx.x] = tmp[0];
}

__global__ __launch_bounds__(512) void scan_top(int* __restrict__ part) {
  __shared__ int tmp[512];
  int t = threadIdx.x;
  int v = (t < 391) ? part[t] : 0;
  tmp[t] = v;
  __syncthreads();
  for (int s = 1; s < 512; s <<= 1) {
    int a = (t >= s) ? tmp[t - s] : 0;
    __syncthreads();
    tmp[t] += a;
    __syncthreads();
  }
  if (t < 391) part[t] = tmp[t] - v;   // exclusive
}

__global__ __launch_bounds__(256) void scan_fin(const int* __restrict__ deg,
                                                const int* __restrict__ part,
                                                int* __restrict__ row_ptr) {
  __shared__ int tmp[256];
  int i = blockIdx.x * 256 + threadIdx.x;
  int t = threadIdx.x;
  int v = (i < NN) ? deg[i] : 0;
  tmp[t] = v;
  __syncthreads();
  for (int s = 1; s < 256; s <<= 1) {
    int a = (t >= s) ? tmp[t - s] : 0;
    __syncthreads();
    tmp[t] += a;
    __syncthreads();
  }
  if (i < NN) row_ptr[i] = tmp[t] - v + part[blockIdx.x];
  if (i == 0) row_ptr[NN] = EE;
}

__global__ __launch_bounds__(256) void scatter_ids(const int* __restrict__ src,
                                                   const int* __restrict__ dst,
                                                   const int* __restrict__ row_ptr,
                                                   const int* __restrict__ slot,
                                                   int* __restrict__ csr_src) {
  int e = blockIdx.x * 256 + threadIdx.x;
  if (e < EE) csr_src[row_ptr[dst[e]] + slot[e]] = src[e];
}

// ---------- gather + mean: one wave/node, pipelined, swizzled output ----------
__global__ __launch_bounds__(256) void gather_mean(
    const unsigned short* __restrict__ h2, const float* __restrict__ csIn,
    const float* __restrict__ cqIn, const float* __restrict__ g,
    const float* __restrict__ beta, const int* __restrict__ csr_src,
    const int* __restrict__ row_ptr, unsigned short* __restrict__ mean_sw) {
  const int lane = threadIdx.x & 63;
  const int node = (blockIdx.x << 2) + (threadIdx.x >> 6);
  if (node >= 100096) return;
  const int c0 = lane * 2;
  float mu0 = csIn[c0] * (1.f / NN), mu1 = csIn[c0 + 1] * (1.f / NN);
  float va0 = cqIn[c0] * (1.f / NN) - mu0 * mu0, va1 = cqIn[c0 + 1] * (1.f / NN) - mu1 * mu1;
  float s0 = g[c0] * rsqrtf(fmaxf(va0, 0.f) + 1e-5f);
  float s1 = g[c0 + 1] * rsqrtf(fmaxf(va1, 0.f) + 1e-5f);
  float t0 = beta[c0] - mu0 * s0, t1 = beta[c0 + 1] - mu1 * s1;
  float a0 = 0.f, a1 = 0.f, rc = 0.f;
  if (node < NN) {
    const int beg = row_ptr[node], end = row_ptr[node + 1];
    int e = beg;
    for (; e + 4 <= end; e += 4) {
      int n0 = csr_src[e], n1 = csr_src[e + 1], n2 = csr_src[e + 2], n3 = csr_src[e + 3];
      unsigned u0 = *(const unsigned*)(h2 + (size_t)n0 * 128 + c0);
      unsigned u1 = *(const unsigned*)(h2 + (size_t)n1 * 128 + c0);
      unsigned u2 = *(const unsigned*)(h2 + (size_t)n2 * 128 + c0);
      unsigned u3 = *(const unsigned*)(h2 + (size_t)n3 * 128 + c0);
      a0 += fmaxf(b2f((unsigned short)u0) * s0 + t0, 0.f);
      a1 += fmaxf(b2f((unsigned short)(u0 >> 16)) * s1 + t1, 0.f);
      a0 += fmaxf(b2f((unsigned short)u1) * s0 + t0, 0.f);
      a1 += fmaxf(b2f((unsigned short)(u1 >> 16)) * s1 + t1, 0.f);
      a0 += fmaxf(b2f((unsigned short)u2) * s0 + t0, 0.f);
      a1 += fmaxf(b2f((unsigned short)(u2 >> 16)) * s1 + t1, 0.f);
      a0 += fmaxf(b2f((unsigned short)u3) * s0 + t0, 0.f);
      a1 += fmaxf(b2f((unsigned short)(u3 >> 16)) * s1 + t1, 0.f);
    }
    if (e + 2 <= end) {
      int n0 = csr_src[e], n1 = csr_src[e + 1];
      unsigned u0 = *(const unsigned*)(h2 + (size_t)n0 * 128 + c0);
      unsigned u1 = *(const unsigned*)(h2 + (size_t)n1 * 128 + c0);
      a0 += fmaxf(b2f((unsigned short)u0) * s0 + t0, 0.f);
      a1 += fmaxf(b2f((unsigned short)(u0 >> 16)) * s1 + t1, 0.f);
      a0 += fmaxf(b2f((unsigned short)u1) * s0 + t0, 0.f);
      a1 += fmaxf(b2f((unsigned short)(u1 >> 16)) * s1 + t1, 0.f);
      e += 2;
    }
    if (e < end) {
      int n0 = csr_src[e];
      unsigned u0 = *(const unsigned*)(h2 + (size_t)n0 * 128 + c0);
      a0 += fmaxf(b2f((unsigned short)u0) * s0 + t0, 0.f);
      a1 += fmaxf(b2f((unsigned short)(u0 >> 16)) * s1 + t1, 0.f);
    }
    int d = end - beg;
    rc = (d > 0) ? 1.f / (float)d : 0.f;
  }
  // swizzled write matching gl2lds consumption
  int r = node & 127, t = node >> 7;
  int kk = (lane >> 2) ^ (r & 7);
  unsigned out = ((unsigned)f2b(a1 * rc) << 16) | (unsigned)f2b(a0 * rc);
  *(unsigned*)(mean_sw + (size_t)(t * 2048 + r * 16 + kk) * 8 + (lane & 3) * 2) = out;
}

// ---------- final normalize -> fp32 out (inline stats) ----------
__global__ __launch_bounds__(256) void norm_out(
    const unsigned short* __restrict__ h, const float* __restrict__ csIn,
    const float* __restrict__ cqIn, const float* __restrict__ g,
    const float* __restrict__ beta, float* __restrict__ out) {
  __shared__ float scs[128], shs[128];
  const int tid = threadIdx.x;
  if (tid < 128) {
    float mu = csIn[tid] * (1.f / NN);
    float var = cqIn[tid] * (1.f / NN) - mu * mu;
    float s = g[tid] * rsqrtf(fmaxf(var, 0.f) + 1e-5f);
    scs[tid] = s;
    shs[tid] = beta[tid] - mu * s;
  }
  __syncthreads();
  size_t e = ((size_t)blockIdx.x * 256 + tid) * 8;
  u16x8 v = *(const u16x8*)(h + e);
  int cb = (int)(e & 127);
  f32x4 sA = *(const f32x4*)&scs[cb], sB = *(const f32x4*)&scs[cb + 4];
  f32x4 tA = *(const f32x4*)&shs[cb], tB = *(const f32x4*)&shs[cb + 4];
  f32x4 o0, o1;
  o0.x = fmaxf(b2f(v[0]) * sA.x + tA.x, 0.f);
  o0.y = fmaxf(b2f(v[1]) * sA.y + tA.y, 0.f);
  o0.z = fmaxf(b2f(v[2]) * sA.z + tA.z, 0.f);
  o0.w = fmaxf(b2f(v[3]) * sA.w + tA.w, 0.f);
  o1.x = fmaxf(b2f(v[4]) * sB.x + tB.x, 0.f);
  o1.y = fmaxf(b2f(v[5]) * sB.y + tB.y, 0.f);
  o1.z = fmaxf(b2f(v[6]) * sB.z + tB.z, 0.f);
  o1.w = fmaxf(b2f(v[7]) * sB.w + tB.w, 0.f);
  *(f32x4*)(out + e) = o0;
  *(f32x4*)(out + e + 4) = o1;
}

extern "C" void kernel_launch(void* const* d_in, const int* in_sizes, int n_in,
                              void* d_out, int out_size, void* d_ws, size_t ws_size,
                              hipStream_t stream) {
  (void)in_sizes; (void)n_in; (void)out_size; (void)ws_size;
  const float* feat = (const float*)d_in[0];
  const int* src = (const int*)d_in[1];
  const int* dst = (const int*)d_in[2];
  const float* aW1 = (const float*)d_in[3];
  const float* aW2 = (const float*)d_in[4];
  const float* sW1 = (const float*)d_in[5];
  const float* sW2 = (const float*)d_in[6];
  const float* cW1 = (const float*)d_in[7];
  const float* cW2 = (const float*)d_in[8];
  // layer order: 0=aggr1 1=aggr2 2=self1 3=self2 4=comb1 5=comb2
  const float* g[6] = {(const float*)d_in[10], (const float*)d_in[13],
                       (const float*)d_in[16], (const float*)d_in[19],
                       (const float*)d_in[22], (const float*)d_in[25]};
  const float* be[6] = {(const float*)d_in[11], (const float*)d_in[14],
                        (const float*)d_in[17], (const float*)d_in[20],
                        (const float*)d_in[23], (const float*)d_in[26]};

  char* ws = (char*)d_ws;
  const size_t S = 25624576;                                   // 782 tiles * 32768 B
  unsigned short* WA = (unsigned short*)ws;                    // h1 / mean_sw
  unsigned short* WB = (unsigned short*)(ws + S);              // h2 / h6
  unsigned short* WC = (unsigned short*)(ws + 2 * S);          // h3 / h5
  int* row_ptr = (int*)(ws + 76873728);                        // 400,128 B
  int* deg = (int*)(ws + 77273856);                            // 400,000 B
  float* stats = (float*)(ws + 77673856);                      // 12,288 B
  int* slot = (int*)(ws + 77686144);                           // 2,560,000 B
  int* part = (int*)(ws + 80246144);                           // 2,048 B
  int* csr_src = (int*)(ws + 80248192);                        // 2,560,000 B
  unsigned short* wt = (unsigned short*)(ws + 82808192);       // 229,376 B
  float* outF = (float*)d_out;
  unsigned short* h4 = (unsigned short*)d_out;                 // park h4 (bf16) in d_out bytes

  float* CS[6]; float* CQ[6];
  for (int L = 0; L < 6; ++L) {
    CS[L] = stats + L * 512;
    CQ[L] = stats + L * 512 + 128;
  }

  hipMemsetAsync(deg, 0, 412288, stream);                      // deg + stats accumulators
  prep_wt<<<112, 256, 0, stream>>>(aW1, aW2, sW1, sW2, cW1, cW2, wt);

  // CSR build (independent of GEMM chain)
  hist_slot<<<2500, 256, 0, stream>>>(dst, deg, slot);
  scan_part<<<391, 256, 0, stream>>>(deg, part);
  scan_top<<<1, 512, 0, stream>>>(part);
  scan_fin<<<391, 256, 0, stream>>>(deg, part, row_ptr);
  scatter_ids<<<2500, 256, 0, stream>>>(src, dst, row_ptr, slot, csr_src);

  GArg a{}, b{};
  // G1: L1+L3 batched (A = fp32 feat)
  a = {feat, nullptr, nullptr, nullptr, nullptr, nullptr, wt + 0 * 16384, WA, CS[0], CQ[0]};
  b = {feat, nullptr, nullptr, nullptr, nullptr, nullptr, wt + 2 * 16384, WC, CS[2], CQ[2]};
  gemm_bn<1, 0><<<dim3(782, 2), 512, 0, stream>>>(a, b);
  // G2: L2+L4 batched (A = h1 / h3, MODE1)
  a = {WA, nullptr, CS[0], CQ[0], g[0], be[0], wt + 1 * 16384, WB, CS[1], CQ[1]};
  b = {WC, nullptr, CS[2], CQ[2], g[2], be[2], wt + 3 * 16384, h4, CS[3], CQ[3]};
  gemm_bn<1, 1><<<dim3(782, 2), 512, 0, stream>>>(a, b);
  // gather: mean of n(h2[src]) per dst -> WA (swizzled; h1 dead)
  gather_mean<<<25024, 256, 0, stream>>>(WB, CS[1], CQ[1], g[1], be[1],
                                         csr_src, row_ptr, WA);
  // G3: L5 = [n(h4) | mean] -> h5 (WC; h3 dead)
  a = {h4, WA, CS[3], CQ[3], g[3], be[3], wt + 4 * 16384, WC, CS[4], CQ[4]};
  gemm_bn<2, 2><<<dim3(782, 1), 512, 0, stream>>>(a, a);
  // G4: L6 = n(h5) -> h6 (WB; h2 dead)
  a = {WC, nullptr, CS[4], CQ[4], g[4], be[4], wt + 6 * 16384, WB, CS[5], CQ[5]};
  gemm_bn<1, 1><<<dim3(782, 1), 512, 0, stream>>>(a, a);
  // final normalize -> fp32 out
  norm_out<<<6250, 256, 0, stream>>>(WB, CS[5], CQ[5], g[5], be[5], outF);
}